// Round 1
// baseline (248.939 us; speedup 1.0000x reference)
//
#include <hip/hip_runtime.h>

// Problem constants
#define BB 2
#define HH 8
#define LL 2048
#define DK 64
#define AD 512

typedef short sh8 __attribute__((ext_vector_type(8)));   // 8 bf16 (4 VGPRs)
typedef float fx4 __attribute__((ext_vector_type(4)));   // MFMA accumulator

__device__ __forceinline__ unsigned short f2bf(float f) {
    union { float f; unsigned u; } v; v.f = f;
    unsigned r = v.u + 0x7FFFu + ((v.u >> 16) & 1u);   // RNE
    return (unsigned short)(r >> 16);
}

// ---------------- convert fp32 inputs -> bf16 [3][4096][512] ----------------
__global__ __launch_bounds__(256) void cvt_inputs(const float* __restrict__ x0,
                                                  const float* __restrict__ x1,
                                                  const float* __restrict__ x2,
                                                  unsigned short* __restrict__ out) {
    const float* src = blockIdx.z == 0 ? x0 : (blockIdx.z == 1 ? x1 : x2);
    unsigned short* dst = out + (size_t)blockIdx.z * (4096 * 512);
    const int n = 4096 * 512 / 4;
    for (int i = blockIdx.x * blockDim.x + threadIdx.x; i < n; i += gridDim.x * blockDim.x) {
        float4 v = ((const float4*)src)[i];
        ushort4 o;
        o.x = f2bf(v.x); o.y = f2bf(v.y); o.z = f2bf(v.z); o.w = f2bf(v.w);
        ((ushort4*)dst)[i] = o;
    }
}

// ---------------- transpose+convert weights: W[512][512] -> Wt bf16 [N][K] ----------------
__global__ __launch_bounds__(256) void transpose_w(const float* __restrict__ w0,
                                                   const float* __restrict__ w1,
                                                   const float* __restrict__ w2,
                                                   const float* __restrict__ w3,
                                                   unsigned short* __restrict__ out) {
    const float* W = blockIdx.z == 0 ? w0 : blockIdx.z == 1 ? w1 : blockIdx.z == 2 ? w2 : w3;
    unsigned short* Wt = out + (size_t)blockIdx.z * (512 * 512);
    __shared__ float t[32][33];
    int tx = threadIdx.x, ty = threadIdx.y;
    int bx = blockIdx.x, by = blockIdx.y;
    #pragma unroll
    for (int i = 0; i < 4; ++i)
        t[ty + i * 8][tx] = W[(size_t)(by * 32 + ty + i * 8) * 512 + bx * 32 + tx];
    __syncthreads();
    #pragma unroll
    for (int i = 0; i < 4; ++i)
        Wt[(size_t)(bx * 32 + ty + i * 8) * 512 + by * 32 + tx] = f2bf(t[tx][ty + i * 8]);
}

// ---------------- pack mask int32 -> 1 bit per key ----------------
__global__ __launch_bounds__(256) void pack_mask(const int* __restrict__ mask,
                                                 unsigned long long* __restrict__ mp) {
    int gid = blockIdx.x * 256 + threadIdx.x;          // one thread per mask element
    int v = mask[gid];
    unsigned long long bal = __ballot(v != 0);
    if ((threadIdx.x & 63) == 0) mp[gid >> 6] = bal;
}

// ---------------- GEMM: C[4096,512] = A_bf16[4096,512] @ Wt^T + bias ----------------
// Wt stored transposed [N][K]. MODE 0: out bf16 to qkv layout [z][B][H][L][64] (scale q).
// MODE 1: out fp32 row-major [4096][512].
template <int MODE>
__global__ __launch_bounds__(256) void gemm_k(const unsigned short* __restrict__ Aall,
                                              const unsigned short* __restrict__ Wtall,
                                              const float* __restrict__ b0,
                                              const float* __restrict__ b1,
                                              const float* __restrict__ b2,
                                              void* __restrict__ outp) {
    const int z = blockIdx.z;
    const unsigned short* A  = Aall  + (size_t)z * (4096 * 512);
    const unsigned short* Bt = Wtall + (size_t)z * (512 * 512);
    const float* bias = (MODE == 0) ? (z == 0 ? b0 : (z == 1 ? b1 : b2)) : b0;

    __shared__ __align__(16) unsigned short As[128][72];
    __shared__ __align__(16) unsigned short Bs[64][72];

    const int tid = threadIdx.x;
    const int wid = tid >> 6, lane = tid & 63, lr = lane & 15, lg = lane >> 4;
    const int wr = wid >> 1, wc = wid & 1;
    const int mblk = blockIdx.x * 128, nblk = blockIdx.y * 64;

    fx4 acc[4][2];
    #pragma unroll
    for (int mf = 0; mf < 4; ++mf)
        #pragma unroll
        for (int nf = 0; nf < 2; ++nf)
            #pragma unroll
            for (int j = 0; j < 4; ++j) acc[mf][nf][j] = 0.f;

    for (int kt = 0; kt < 8; ++kt) {
        __syncthreads();
        #pragma unroll
        for (int i = tid; i < 1024; i += 256) {
            int r = i >> 3, s = (i & 7) * 8;
            *(sh8*)&As[r][s] = *(const sh8*)(A + (size_t)(mblk + r) * 512 + kt * 64 + s);
        }
        #pragma unroll
        for (int i = tid; i < 512; i += 256) {
            int r = i >> 3, s = (i & 7) * 8;
            *(sh8*)&Bs[r][s] = *(const sh8*)(Bt + (size_t)(nblk + r) * 512 + kt * 64 + s);
        }
        __syncthreads();
        #pragma unroll
        for (int d = 0; d < 2; ++d) {
            sh8 af[4], bf[2];
            #pragma unroll
            for (int mf = 0; mf < 4; ++mf)
                af[mf] = *(const sh8*)&As[wr * 64 + mf * 16 + lr][d * 32 + lg * 8];
            #pragma unroll
            for (int nf = 0; nf < 2; ++nf)
                bf[nf] = *(const sh8*)&Bs[wc * 32 + nf * 16 + lr][d * 32 + lg * 8];
            #pragma unroll
            for (int mf = 0; mf < 4; ++mf)
                #pragma unroll
                for (int nf = 0; nf < 2; ++nf)
                    acc[mf][nf] = __builtin_amdgcn_mfma_f32_16x16x32_bf16(af[mf], bf[nf], acc[mf][nf], 0, 0, 0);
        }
    }

    #pragma unroll
    for (int nf = 0; nf < 2; ++nf) {
        int n = nblk + wc * 32 + nf * 16 + lr;
        float bv = bias[n];
        #pragma unroll
        for (int mf = 0; mf < 4; ++mf) {
            #pragma unroll
            for (int j = 0; j < 4; ++j) {
                int m = mblk + wr * 64 + mf * 16 + lg * 4 + j;
                float val = acc[mf][nf][j] + bv;
                if (MODE == 0) {
                    if (z == 2) val *= 0.125f;          // 1/sqrt(D_K) folded into q
                    int bb = m >> 11, lq = m & 2047, h = n >> 6, dd = n & 63;
                    ((unsigned short*)outp)[(size_t)(((z * 2 + bb) * 8 + h) * 2048 + lq) * 64 + dd] = f2bf(val);
                } else {
                    ((float*)outp)[(size_t)m * 512 + n] = val;
                }
            }
        }
    }
}

// ---------------- fused attention: per (b,h,q-block of 64) ----------------
// pass1: online (m,l); pass2: recompute S, write normalized aw, accumulate PV.
__global__ __launch_bounds__(256) void attn_k(const unsigned short* __restrict__ qkv,
                                              const unsigned long long* __restrict__ mp,
                                              float* __restrict__ aw,
                                              unsigned short* __restrict__ cv) {
    const int qb = blockIdx.x;          // 0..31
    const int bh = blockIdx.y;          // 0..15
    const int b = bh >> 3, h = bh & 7;
    const unsigned short* Kg = qkv + (size_t)bh * (2048 * 64);
    const unsigned short* Vg = qkv + (size_t)(1 * 2097152) + (size_t)bh * (2048 * 64);
    const unsigned short* Qg = qkv + (size_t)(2 * 2097152) + (size_t)bh * (2048 * 64) + (size_t)qb * 64 * 64;

    __shared__ __align__(16) unsigned short Qs[64][72];
    __shared__ __align__(16) unsigned short Ks[64][72];
    __shared__ __align__(16) unsigned short Vt[64][72];
    __shared__ __align__(16) unsigned short Ps[64][72];

    const int tid = threadIdx.x;
    const int wid = tid >> 6, lane = tid & 63, lr = lane & 15, lg = lane >> 4;

    // stage Q once
    for (int i = tid; i < 512; i += 256) {
        int r = i >> 3, s = (i & 7) * 8;
        *(sh8*)&Qs[r][s] = *(const sh8*)(Qg + r * 64 + s);
    }
    __syncthreads();
    sh8 qf[2];
    qf[0] = *(const sh8*)&Qs[wid * 16 + lr][lg * 8];
    qf[1] = *(const sh8*)&Qs[wid * 16 + lr][32 + lg * 8];

    float m_[4], l_[4];
    #pragma unroll
    for (int j = 0; j < 4; ++j) { m_[j] = -3e38f; l_[j] = 0.f; }
    const int qrow0 = qb * 64 + wid * 16 + lg * 4;     // + j

    // ---------- pass 1: softmax stats ----------
    for (int kt = 0; kt < 32; ++kt) {
        __syncthreads();
        for (int i = tid; i < 512; i += 256) {
            int r = i >> 3, s = (i & 7) * 8;
            *(sh8*)&Ks[r][s] = *(const sh8*)(Kg + (size_t)(kt * 64 + r) * 64 + s);
        }
        __syncthreads();
        fx4 acc[4];
        #pragma unroll
        for (int nt = 0; nt < 4; ++nt) { acc[nt][0]=0.f; acc[nt][1]=0.f; acc[nt][2]=0.f; acc[nt][3]=0.f; }
        #pragma unroll
        for (int nt = 0; nt < 4; ++nt)
            #pragma unroll
            for (int d = 0; d < 2; ++d) {
                sh8 kf = *(const sh8*)&Ks[nt * 16 + lr][d * 32 + lg * 8];
                acc[nt] = __builtin_amdgcn_mfma_f32_16x16x32_bf16(qf[d], kf, acc[nt], 0, 0, 0);
            }
        #pragma unroll
        for (int j = 0; j < 4; ++j) {
            unsigned long long mw = mp[(size_t)(b * 2048 + qrow0 + j) * 32 + kt];
            float s0[4];
            float tmax = -3e38f;
            #pragma unroll
            for (int nt = 0; nt < 4; ++nt) {
                bool ok = (mw >> (nt * 16 + lr)) & 1ull;
                s0[nt] = ok ? acc[nt][j] : -3e38f;
                tmax = fmaxf(tmax, s0[nt]);
            }
            #pragma unroll
            for (int off = 1; off < 16; off <<= 1) tmax = fmaxf(tmax, __shfl_xor(tmax, off));
            float mnew = fmaxf(m_[j], tmax);
            float psum = 0.f;
            #pragma unroll
            for (int nt = 0; nt < 4; ++nt) {
                bool ok = (mw >> (nt * 16 + lr)) & 1ull;
                psum += ok ? __expf(s0[nt] - mnew) : 0.f;
            }
            #pragma unroll
            for (int off = 1; off < 16; off <<= 1) psum += __shfl_xor(psum, off);
            l_[j] = l_[j] * __expf(m_[j] - mnew) + psum;
            m_[j] = mnew;
        }
    }

    float rinv[4];
    #pragma unroll
    for (int j = 0; j < 4; ++j) { l_[j] = fmaxf(l_[j], 1e-30f); rinv[j] = 1.0f / l_[j]; }

    // ---------- pass 2: aw write + PV ----------
    fx4 cacc[4];
    #pragma unroll
    for (int dn = 0; dn < 4; ++dn) { cacc[dn][0]=0.f; cacc[dn][1]=0.f; cacc[dn][2]=0.f; cacc[dn][3]=0.f; }
    float* awb = aw + (size_t)bh * 2048 * 2048 + (size_t)(qb * 64) * 2048;

    for (int kt = 0; kt < 32; ++kt) {
        __syncthreads();
        for (int i = tid; i < 512; i += 256) {
            int r = i >> 3, s = (i & 7) * 8;
            *(sh8*)&Ks[r][s] = *(const sh8*)(Kg + (size_t)(kt * 64 + r) * 64 + s);
        }
        for (int i = tid; i < 512; i += 256) {
            int r = i >> 3, s = (i & 7) * 8;
            sh8 v = *(const sh8*)(Vg + (size_t)(kt * 64 + r) * 64 + s);
            #pragma unroll
            for (int e = 0; e < 8; ++e) Vt[s + e][r] = ((unsigned short*)&v)[e];
        }
        __syncthreads();
        fx4 acc[4];
        #pragma unroll
        for (int nt = 0; nt < 4; ++nt) { acc[nt][0]=0.f; acc[nt][1]=0.f; acc[nt][2]=0.f; acc[nt][3]=0.f; }
        #pragma unroll
        for (int nt = 0; nt < 4; ++nt)
            #pragma unroll
            for (int d = 0; d < 2; ++d) {
                sh8 kf = *(const sh8*)&Ks[nt * 16 + lr][d * 32 + lg * 8];
                acc[nt] = __builtin_amdgcn_mfma_f32_16x16x32_bf16(qf[d], kf, acc[nt], 0, 0, 0);
            }
        #pragma unroll
        for (int j = 0; j < 4; ++j) {
            unsigned long long mw = mp[(size_t)(b * 2048 + qrow0 + j) * 32 + kt];
            #pragma unroll
            for (int nt = 0; nt < 4; ++nt) {
                bool ok = (mw >> (nt * 16 + lr)) & 1ull;
                float p = ok ? __expf(acc[nt][j] - m_[j]) * rinv[j] : 0.f;
                awb[(size_t)(wid * 16 + lg * 4 + j) * 2048 + kt * 64 + nt * 16 + lr] = p;
                Ps[wid * 16 + lg * 4 + j][nt * 16 + lr] = f2bf(p);
            }
        }
        __syncthreads();
        #pragma unroll
        for (int dn = 0; dn < 4; ++dn)
            #pragma unroll
            for (int ks = 0; ks < 2; ++ks) {
                sh8 pf = *(const sh8*)&Ps[wid * 16 + lr][ks * 32 + lg * 8];
                sh8 vf = *(const sh8*)&Vt[dn * 16 + lr][ks * 32 + lg * 8];
                cacc[dn] = __builtin_amdgcn_mfma_f32_16x16x32_bf16(pf, vf, cacc[dn], 0, 0, 0);
            }
    }

    #pragma unroll
    for (int dn = 0; dn < 4; ++dn)
        #pragma unroll
        for (int j = 0; j < 4; ++j) {
            int q = qb * 64 + wid * 16 + lg * 4 + j;
            cv[(size_t)(b * 2048 + q) * 512 + h * 64 + dn * 16 + lr] = f2bf(cacc[dn][j]);
        }
}

// ---------------- launch ----------------
extern "C" void kernel_launch(void* const* d_in, const int* in_sizes, int n_in,
                              void* d_out, int out_size, void* d_ws, size_t ws_size,
                              hipStream_t stream) {
    const float* key_in   = (const float*)d_in[0];
    const float* value_in = (const float*)d_in[1];
    const float* query_in = (const float*)d_in[2];
    const float* Wk = (const float*)d_in[3];
    const float* bk = (const float*)d_in[4];
    const float* Wv = (const float*)d_in[5];
    const float* bv = (const float*)d_in[6];
    const float* Wq = (const float*)d_in[7];
    const float* bq = (const float*)d_in[8];
    const float* Wo = (const float*)d_in[9];
    const float* bo = (const float*)d_in[10];
    const int* mask = (const int*)d_in[11];

    char* ws = (char*)d_ws;
    unsigned short* in_bf = (unsigned short*)(ws);                    // 3*4096*512*2  = 12,582,912
    unsigned short* qkv   = (unsigned short*)(ws + 12582912);         // 3*4096*512*2  -> 25,165,824
    unsigned short* wt    = (unsigned short*)(ws + 25165824);         // 4*512*512*2   -> 27,262,976
    unsigned short* cvb   = (unsigned short*)(ws + 27262976);         // 4096*512*2    -> 31,457,280
    unsigned long long* mpk = (unsigned long long*)(ws + 31457280);   // 131072*8      -> 32,505,856

    float* out_cv = (float*)d_out;
    float* out_aw = (float*)d_out + 2097152;

    cvt_inputs<<<dim3(512, 1, 3), 256, 0, stream>>>(key_in, value_in, query_in, in_bf);
    transpose_w<<<dim3(16, 16, 4), dim3(32, 8), 0, stream>>>(Wk, Wv, Wq, Wo, wt);
    pack_mask<<<dim3(32768), 256, 0, stream>>>(mask, mpk);
    gemm_k<0><<<dim3(32, 8, 3), 256, 0, stream>>>(in_bf, wt, bk, bv, bq, qkv);
    attn_k<<<dim3(32, 16), 256, 0, stream>>>(qkv, mpk, out_aw, cvb);
    gemm_k<1><<<dim3(32, 8, 1), 256, 0, stream>>>(cvb, wt + 3 * 512 * 512, bo, bo, bo, out_cv);
}

// Round 2
// 201.544 us; speedup vs baseline: 1.2352x; 1.2352x over previous
//
#include <hip/hip_runtime.h>

typedef short sh8 __attribute__((ext_vector_type(8)));   // 8 bf16
typedef float fx4 __attribute__((ext_vector_type(4)));   // MFMA accumulator

__device__ __forceinline__ unsigned short f2bf(float f) {
    union { float f; unsigned u; } v; v.f = f;
    unsigned r = v.u + 0x7FFFu + ((v.u >> 16) & 1u);   // RNE
    return (unsigned short)(r >> 16);
}
__device__ __forceinline__ unsigned pk2(float a, float b) {
    return (unsigned)f2bf(a) | ((unsigned)f2bf(b) << 16);
}

// ---------------- convert fp32 inputs -> bf16 [3][4096][512] ----------------
__global__ __launch_bounds__(256) void cvt_inputs(const float* __restrict__ x0,
                                                  const float* __restrict__ x1,
                                                  const float* __restrict__ x2,
                                                  unsigned short* __restrict__ out) {
    const float* src = blockIdx.z == 0 ? x0 : (blockIdx.z == 1 ? x1 : x2);
    unsigned short* dst = out + (size_t)blockIdx.z * (4096 * 512);
    const int n = 4096 * 512 / 4;
    for (int i = blockIdx.x * blockDim.x + threadIdx.x; i < n; i += gridDim.x * blockDim.x) {
        float4 v = ((const float4*)src)[i];
        ushort4 o;
        o.x = f2bf(v.x); o.y = f2bf(v.y); o.z = f2bf(v.z); o.w = f2bf(v.w);
        ((ushort4*)dst)[i] = o;
    }
}

// ---------------- transpose+convert weights: W[512][512] -> Wt bf16 [N][K] ----------------
__global__ __launch_bounds__(256) void transpose_w(const float* __restrict__ w0,
                                                   const float* __restrict__ w1,
                                                   const float* __restrict__ w2,
                                                   const float* __restrict__ w3,
                                                   unsigned short* __restrict__ out) {
    const float* W = blockIdx.z == 0 ? w0 : blockIdx.z == 1 ? w1 : blockIdx.z == 2 ? w2 : w3;
    unsigned short* Wt = out + (size_t)blockIdx.z * (512 * 512);
    __shared__ float t[32][33];
    int tx = threadIdx.x, ty = threadIdx.y;
    int bx = blockIdx.x, by = blockIdx.y;
    #pragma unroll
    for (int i = 0; i < 4; ++i)
        t[ty + i * 8][tx] = W[(size_t)(by * 32 + ty + i * 8) * 512 + bx * 32 + tx];
    __syncthreads();
    #pragma unroll
    for (int i = 0; i < 4; ++i)
        Wt[(size_t)(bx * 32 + ty + i * 8) * 512 + by * 32 + tx] = f2bf(t[tx][ty + i * 8]);
}

// ---------------- pack mask row 0 per batch -> 1 bit/key (mask is q-uniform) --------------
__global__ __launch_bounds__(256) void pack_mask2(const int* __restrict__ mask,
                                                  unsigned long long* __restrict__ mp2) {
    int b = blockIdx.y, k = blockIdx.x * 256 + threadIdx.x;
    int v = mask[(size_t)b * 4194304 + k];
    unsigned long long bal = __ballot(v != 0);
    if ((threadIdx.x & 63) == 0) mp2[b * 32 + (k >> 6)] = bal;
}

// ---------------- GEMM: C[4096,512] = A_bf16 @ Wt^T + bias ----------------
template <int MODE>
__global__ __launch_bounds__(256) void gemm_k(const unsigned short* __restrict__ Aall,
                                              const unsigned short* __restrict__ Wtall,
                                              const float* __restrict__ b0,
                                              const float* __restrict__ b1,
                                              const float* __restrict__ b2,
                                              void* __restrict__ outp) {
    const int z = blockIdx.z;
    const unsigned short* A  = Aall  + (size_t)z * (4096 * 512);
    const unsigned short* Bt = Wtall + (size_t)z * (512 * 512);
    const float* bias = (MODE == 0) ? (z == 0 ? b0 : (z == 1 ? b1 : b2)) : b0;

    __shared__ __align__(16) unsigned short As[128][72];
    __shared__ __align__(16) unsigned short Bs[64][72];

    const int tid = threadIdx.x;
    const int wid = tid >> 6, lane = tid & 63, lr = lane & 15, lg = lane >> 4;
    const int wr = wid >> 1, wc = wid & 1;
    const int mblk = blockIdx.x * 128, nblk = blockIdx.y * 64;

    fx4 acc[4][2];
    #pragma unroll
    for (int mf = 0; mf < 4; ++mf)
        #pragma unroll
        for (int nf = 0; nf < 2; ++nf)
            #pragma unroll
            for (int j = 0; j < 4; ++j) acc[mf][nf][j] = 0.f;

    for (int kt = 0; kt < 8; ++kt) {
        __syncthreads();
        #pragma unroll
        for (int i = tid; i < 1024; i += 256) {
            int r = i >> 3, s = (i & 7) * 8;
            *(sh8*)&As[r][s] = *(const sh8*)(A + (size_t)(mblk + r) * 512 + kt * 64 + s);
        }
        #pragma unroll
        for (int i = tid; i < 512; i += 256) {
            int r = i >> 3, s = (i & 7) * 8;
            *(sh8*)&Bs[r][s] = *(const sh8*)(Bt + (size_t)(nblk + r) * 512 + kt * 64 + s);
        }
        __syncthreads();
        #pragma unroll
        for (int d = 0; d < 2; ++d) {
            sh8 af[4], bf[2];
            #pragma unroll
            for (int mf = 0; mf < 4; ++mf)
                af[mf] = *(const sh8*)&As[wr * 64 + mf * 16 + lr][d * 32 + lg * 8];
            #pragma unroll
            for (int nf = 0; nf < 2; ++nf)
                bf[nf] = *(const sh8*)&Bs[wc * 32 + nf * 16 + lr][d * 32 + lg * 8];
            #pragma unroll
            for (int mf = 0; mf < 4; ++mf)
                #pragma unroll
                for (int nf = 0; nf < 2; ++nf)
                    acc[mf][nf] = __builtin_amdgcn_mfma_f32_16x16x32_bf16(af[mf], bf[nf], acc[mf][nf], 0, 0, 0);
        }
    }

    #pragma unroll
    for (int nf = 0; nf < 2; ++nf) {
        int n = nblk + wc * 32 + nf * 16 + lr;
        float bv = bias[n];
        #pragma unroll
        for (int mf = 0; mf < 4; ++mf) {
            #pragma unroll
            for (int j = 0; j < 4; ++j) {
                int m = mblk + wr * 64 + mf * 16 + lg * 4 + j;
                float val = acc[mf][nf][j] + bv;
                if (MODE == 0) {
                    if (z == 2) val *= 0.125f;          // 1/sqrt(64) folded into q
                    int bb = m >> 11, lq = m & 2047, h = n >> 6, dd = n & 63;
                    ((unsigned short*)outp)[(size_t)(((z * 2 + bb) * 8 + h) * 2048 + lq) * 64 + dd] = f2bf(val);
                } else {
                    ((float*)outp)[(size_t)m * 512 + n] = val;
                }
            }
        }
    }
}

// ---------------- transpose V: qkv V region [bh][2048][64] -> Vt [bh][64][2048] ----------
__global__ __launch_bounds__(256) void transpose_v(const unsigned short* __restrict__ qkv,
                                                   unsigned short* __restrict__ Vt) {
    const int kb = blockIdx.x, bh = blockIdx.y;
    const unsigned short* Vg = qkv + 2097152 + (size_t)bh * 131072 + kb * 64 * 64;
    __shared__ unsigned short t[64][72];
    int tid = threadIdx.x;
    for (int i = tid; i < 512; i += 256) {
        int r = i >> 3, s = (i & 7) * 8;
        *(sh8*)&t[r][s] = *(const sh8*)(Vg + r * 64 + s);
    }
    __syncthreads();
    for (int i = tid; i < 512; i += 256) {
        int d = i >> 3, kc = (i & 7) * 8;
        unsigned short tmp[8];
        #pragma unroll
        for (int e = 0; e < 8; ++e) tmp[e] = t[kc + e][d];
        *(sh8*)(Vt + (size_t)(bh * 64 + d) * 2048 + kb * 64 + kc) = *(sh8*)tmp;
    }
}

// ---------------- attention stats (pass 1): partial (m,l) per q row, ksplit=4 ------------
// Swapped QK^T: mfma(K,Q) -> S^T; lane holds 16 k-values for one q row -> in-lane reduce.
__global__ __launch_bounds__(256) void attn_stats(const unsigned short* __restrict__ qkv,
                                                  const unsigned long long* __restrict__ mp2,
                                                  float2* __restrict__ sp) {
    const int qb = blockIdx.x, bh = blockIdx.y, ks = blockIdx.z;
    const int b = bh >> 3;
    const unsigned short* Kg = qkv + (size_t)bh * 131072 + (size_t)ks * 512 * 64;
    const unsigned short* Qg = qkv + 2 * 2097152 + (size_t)bh * 131072 + (size_t)qb * 64 * 64;
    const int tid = threadIdx.x, w = tid >> 6, lane = tid & 63, lr = lane & 15, lg = lane >> 4;
    float2* spo = sp + (size_t)ks * 32768 + bh * 2048 + qb * 64;

    unsigned long long mws[8];
    bool any = false;
    #pragma unroll
    for (int kt = 0; kt < 8; ++kt) { mws[kt] = mp2[b * 32 + ks * 8 + kt]; any |= (mws[kt] != 0ull); }
    if (!any) {
        if (tid < 64) spo[tid] = make_float2(-3e38f, 0.f);
        return;
    }

    sh8 qf0 = *(const sh8*)(Qg + (w * 16 + lr) * 64 + lg * 8);
    sh8 qf1 = *(const sh8*)(Qg + (w * 16 + lr) * 64 + 32 + lg * 8);

    float m_ = -3e38f, l_ = 0.f;
    for (int kt = 0; kt < 8; ++kt) {
        unsigned long long mw = mws[kt];
        if (mw == 0ull) continue;
        const unsigned short* Kt = Kg + kt * 64 * 64;
        fx4 accs[4];
        #pragma unroll
        for (int mt = 0; mt < 4; ++mt) {
            sh8 kf0 = *(const sh8*)(Kt + (mt * 16 + lr) * 64 + lg * 8);
            sh8 kf1 = *(const sh8*)(Kt + (mt * 16 + lr) * 64 + 32 + lg * 8);
            fx4 z; z[0] = 0.f; z[1] = 0.f; z[2] = 0.f; z[3] = 0.f;
            z = __builtin_amdgcn_mfma_f32_16x16x32_bf16(kf0, qf0, z, 0, 0, 0);
            accs[mt] = __builtin_amdgcn_mfma_f32_16x16x32_bf16(kf1, qf1, z, 0, 0, 0);
        }
        float sv[16];
        float tmax = -3e38f;
        if (mw == ~0ull) {
            #pragma unroll
            for (int mt = 0; mt < 4; ++mt)
                #pragma unroll
                for (int j = 0; j < 4; ++j) {
                    float s = accs[mt][j];
                    sv[mt * 4 + j] = s; tmax = fmaxf(tmax, s);
                }
        } else {
            #pragma unroll
            for (int mt = 0; mt < 4; ++mt)
                #pragma unroll
                for (int j = 0; j < 4; ++j) {
                    int kl = mt * 16 + lg * 4 + j;
                    bool ok = (mw >> kl) & 1ull;
                    float s = ok ? accs[mt][j] : -3e38f;
                    sv[mt * 4 + j] = s; tmax = fmaxf(tmax, s);
                }
        }
        float mnew = fmaxf(m_, tmax);
        float ps = 0.f;
        #pragma unroll
        for (int i = 0; i < 16; ++i) ps += __expf(sv[i] - mnew);
        l_ = l_ * __expf(m_ - mnew) + ps;
        m_ = mnew;
    }
    // merge across lg groups (lanes ^16, ^32)
    #pragma unroll
    for (int off = 16; off <= 32; off <<= 1) {
        float mo = __shfl_xor(m_, off), lo = __shfl_xor(l_, off);
        float mn = fmaxf(m_, mo);
        l_ = l_ * __expf(m_ - mn) + lo * __expf(mo - mn);
        m_ = mn;
    }
    if (lg == 0) spo[w * 16 + lr] = make_float2(m_, l_);
}

// ---------------- merge stats partials -> (M, 1/L) per row --------------------------------
__global__ __launch_bounds__(256) void stats_merge(const float2* __restrict__ sp,
                                                   float2* __restrict__ st) {
    int r = blockIdx.x * 256 + threadIdx.x;      // 0..32767
    float M = -3e38f;
    float2 v[4];
    #pragma unroll
    for (int ks = 0; ks < 4; ++ks) { v[ks] = sp[(size_t)ks * 32768 + r]; M = fmaxf(M, v[ks].x); }
    float L = 0.f;
    #pragma unroll
    for (int ks = 0; ks < 4; ++ks) L += v[ks].y * __expf(v[ks].x - M);
    float rinv = (L > 0.f) ? 1.f / L : 0.f;
    if (L <= 0.f) M = 0.f;
    st[r] = make_float2(M, rinv);
}

// ---------------- pass 2: recompute S^T, write normalized aw (float4), PV partial ---------
__global__ __launch_bounds__(256) void attn_pass2(const unsigned short* __restrict__ qkv,
                                                  const unsigned short* __restrict__ Vt,
                                                  const unsigned long long* __restrict__ mp2,
                                                  const float2* __restrict__ st,
                                                  float* __restrict__ aw,
                                                  float* __restrict__ ppart) {
    const int qb = blockIdx.x, bh = blockIdx.y, ks = blockIdx.z;   // ks 0..1 (1024 keys each)
    const int b = bh >> 3, h = bh & 7;
    const unsigned short* Kg = qkv + (size_t)bh * 131072 + (size_t)ks * 1024 * 64;
    const unsigned short* Vg = Vt + (size_t)bh * 131072;            // [64 d][2048 k]
    const unsigned short* Qg = qkv + 2 * 2097152 + (size_t)bh * 131072 + (size_t)qb * 64 * 64;

    __shared__ __align__(16) unsigned short Ks[64][64];
    __shared__ __align__(16) unsigned short Vs[64][64];
    __shared__ __align__(16) unsigned short Pb[64][80];

    const int tid = threadIdx.x, w = tid >> 6, lane = tid & 63, lr = lane & 15, lg = lane >> 4;
    const int r7 = lr & 7;
    const int q = qb * 64 + w * 16 + lr;
    float2 mr = st[(size_t)bh * 2048 + q];
    const float M = mr.x, rinv = mr.y;

    sh8 qf0 = *(const sh8*)(Qg + (w * 16 + lr) * 64 + lg * 8);
    sh8 qf1 = *(const sh8*)(Qg + (w * 16 + lr) * 64 + 32 + lg * 8);

    fx4 acco[4];
    #pragma unroll
    for (int md = 0; md < 4; ++md) { acco[md][0] = 0.f; acco[md][1] = 0.f; acco[md][2] = 0.f; acco[md][3] = 0.f; }

    float* awb = aw + (size_t)bh * 4194304 + (size_t)q * 2048 + (size_t)ks * 1024;

    for (int kt = 0; kt < 16; ++kt) {
        unsigned long long mw = mp2[b * 32 + ks * 16 + kt];
        if (mw == 0ull) {                       // block-uniform: zero-fill aw, skip compute
            float4 z4 = {0.f, 0.f, 0.f, 0.f};
            #pragma unroll
            for (int mt = 0; mt < 4; ++mt)
                *(float4*)(awb + kt * 64 + mt * 16 + lg * 4) = z4;
            continue;
        }
        __syncthreads();                        // WAR: prior iteration's frag reads done
        // stage K tile [64k][64d] and V^T tile [64d][64k], XOR-swizzled chunks (c ^= r&7)
        #pragma unroll
        for (int g = 0; g < 2; ++g) {
            int p = tid + g * 256;
            int r = p >> 3, c = p & 7, cs = c ^ (r & 7);
            sh8 kv8 = *(const sh8*)(Kg + (size_t)(kt * 64 + r) * 64 + c * 8);
            *(sh8*)&Ks[r][cs * 8] = kv8;
            sh8 vv8 = *(const sh8*)(Vg + (size_t)r * 2048 + ks * 1024 + kt * 64 + c * 8);
            *(sh8*)&Vs[r][cs * 8] = vv8;
        }
        __syncthreads();                        // RAW: staging visible

        // S^T = K @ Q^T for this wave's 16 q
        fx4 accs[4];
        #pragma unroll
        for (int mt = 0; mt < 4; ++mt) {
            sh8 kf0 = *(const sh8*)&Ks[mt * 16 + lr][((0 + lg) ^ r7) * 8];
            sh8 kf1 = *(const sh8*)&Ks[mt * 16 + lr][((4 + lg) ^ r7) * 8];
            fx4 z; z[0] = 0.f; z[1] = 0.f; z[2] = 0.f; z[3] = 0.f;
            z = __builtin_amdgcn_mfma_f32_16x16x32_bf16(kf0, qf0, z, 0, 0, 0);
            accs[mt] = __builtin_amdgcn_mfma_f32_16x16x32_bf16(kf1, qf1, z, 0, 0, 0);
        }

        // p = exp(s - M) * rinv ; aw float4 stores ; pack bf16 -> Pb
        bool full = (mw == ~0ull);
        #pragma unroll
        for (int mt = 0; mt < 4; ++mt) {
            float4 pw;
            #pragma unroll
            for (int j = 0; j < 4; ++j) {
                int kl = mt * 16 + lg * 4 + j;
                bool ok = full || ((mw >> kl) & 1ull);
                float p = ok ? __expf(accs[mt][j] - M) * rinv : 0.f;
                ((float*)&pw)[j] = p;
            }
            *(float4*)(awb + kt * 64 + mt * 16 + lg * 4) = pw;
            *(uint2*)&Pb[w * 16 + lr][mt * 16 + lg * 4] = make_uint2(pk2(pw.x, pw.y), pk2(pw.z, pw.w));
        }

        // Pb rows are wave-private: wave-level RAW fence only (no __syncthreads)
        asm volatile("s_waitcnt lgkmcnt(0)" ::: "memory");
        __builtin_amdgcn_sched_barrier(0);

        sh8 bp0 = *(const sh8*)&Pb[w * 16 + lr][lg * 8];
        sh8 bp1 = *(const sh8*)&Pb[w * 16 + lr][32 + lg * 8];
        #pragma unroll
        for (int md = 0; md < 4; ++md) {
            sh8 vf0 = *(const sh8*)&Vs[md * 16 + lr][((0 + lg) ^ r7) * 8];
            sh8 vf1 = *(const sh8*)&Vs[md * 16 + lr][((4 + lg) ^ r7) * 8];
            acco[md] = __builtin_amdgcn_mfma_f32_16x16x32_bf16(vf0, bp0, acco[md], 0, 0, 0);
            acco[md] = __builtin_amdgcn_mfma_f32_16x16x32_bf16(vf1, bp1, acco[md], 0, 0, 0);
        }
    }

    float* ppo = ppart + (size_t)ks * 2097152 + (size_t)(b * 2048 + qb * 64 + w * 16 + lr) * 512 + h * 64;
    #pragma unroll
    for (int md = 0; md < 4; ++md)
        *(fx4*)(ppo + md * 16 + lg * 4) = acco[md];
}

// ---------------- reduce PV partials -> cvb bf16 [4096][512] ------------------------------
__global__ __launch_bounds__(256) void pv_reduce(const float* __restrict__ pp,
                                                 unsigned short* __restrict__ cvb) {
    int i = blockIdx.x * 256 + threadIdx.x;          // float4 index, 524288 total
    float4 a = ((const float4*)pp)[i];
    float4 b = ((const float4*)(pp + 2097152))[i];
    ushort4 o;
    o.x = f2bf(a.x + b.x); o.y = f2bf(a.y + b.y);
    o.z = f2bf(a.z + b.z); o.w = f2bf(a.w + b.w);
    ((ushort4*)cvb)[i] = o;
}

// ---------------- launch ----------------
extern "C" void kernel_launch(void* const* d_in, const int* in_sizes, int n_in,
                              void* d_out, int out_size, void* d_ws, size_t ws_size,
                              hipStream_t stream) {
    const float* key_in   = (const float*)d_in[0];
    const float* value_in = (const float*)d_in[1];
    const float* query_in = (const float*)d_in[2];
    const float* Wk = (const float*)d_in[3];
    const float* bk = (const float*)d_in[4];
    const float* Wv = (const float*)d_in[5];
    const float* bv = (const float*)d_in[6];
    const float* Wq = (const float*)d_in[7];
    const float* bq = (const float*)d_in[8];
    const float* Wo = (const float*)d_in[9];
    const float* bo = (const float*)d_in[10];
    const int* mask = (const int*)d_in[11];

    char* ws = (char*)d_ws;
    // [0, 16.78M): ppart (attn phase)  /  in_bf (pre-attn phase, 12.58M) -- disjoint in time
    float*          ppart = (float*)(ws);
    unsigned short* in_bf = (unsigned short*)(ws);
    // [16.78M, 29.36M): qkv (gemm0->attn)  /  cvb overlays after attn (4.19M)
    unsigned short* qkv   = (unsigned short*)(ws + 16777216);
    unsigned short* cvb   = (unsigned short*)(ws + 16777216);
    unsigned short* wt    = (unsigned short*)(ws + 29360128);   // 2.10M
    unsigned short* VtB   = (unsigned short*)(ws + 31457280);   // 4.19M
    unsigned long long* mp2 = (unsigned long long*)(ws + 35651584); // 512 B (pad 1K)
    float2*         sp    = (float2*)(ws + 35652608);           // 1.05M
    float2*         stt   = (float2*)(ws + 36701184);           // 0.26M -> end ~37.0M

    float* out_cv = (float*)d_out;
    float* out_aw = (float*)d_out + 2097152;

    cvt_inputs<<<dim3(512, 1, 3), 256, 0, stream>>>(key_in, value_in, query_in, in_bf);
    transpose_w<<<dim3(16, 16, 4), dim3(32, 8), 0, stream>>>(Wk, Wv, Wq, Wo, wt);
    pack_mask2<<<dim3(8, 2), 256, 0, stream>>>(mask, mp2);
    gemm_k<0><<<dim3(32, 8, 3), 256, 0, stream>>>(in_bf, wt, bk, bv, bq, qkv);
    transpose_v<<<dim3(32, 16), 256, 0, stream>>>(qkv, VtB);
    attn_stats<<<dim3(32, 16, 4), 256, 0, stream>>>(qkv, mp2, sp);
    stats_merge<<<dim3(128), 256, 0, stream>>>(sp, stt);
    attn_pass2<<<dim3(32, 16, 2), 256, 0, stream>>>(qkv, VtB, mp2, stt, out_aw, ppart);
    pv_reduce<<<dim3(2048), 256, 0, stream>>>(ppart, cvb);
    gemm_k<1><<<dim3(32, 8, 1), 256, 0, stream>>>(cvb, wt + 3 * 262144, bo, bo, bo, out_cv);
}

// Round 3
// 185.313 us; speedup vs baseline: 1.3433x; 1.0876x over previous
//
#include <hip/hip_runtime.h>

typedef short sh8 __attribute__((ext_vector_type(8)));   // 8 bf16
typedef float fx4 __attribute__((ext_vector_type(4)));   // MFMA accumulator

__device__ __forceinline__ unsigned short f2bf(float f) {
    union { float f; unsigned u; } v; v.f = f;
    unsigned r = v.u + 0x7FFFu + ((v.u >> 16) & 1u);   // RNE
    return (unsigned short)(r >> 16);
}
__device__ __forceinline__ unsigned pk2(float a, float b) {
    return (unsigned)f2bf(a) | ((unsigned)f2bf(b) << 16);
}
// async global->LDS, 16B per lane; LDS dest = wave-uniform base + lane*16
__device__ __forceinline__ void gl16(const unsigned short* g, unsigned short* l) {
    __builtin_amdgcn_global_load_lds(
        (const __attribute__((address_space(1))) unsigned int*)g,
        (__attribute__((address_space(3))) unsigned int*)l, 16, 0, 0);
}

// ---------------- convert fp32 inputs -> bf16 [3][4096][512] ----------------
__global__ __launch_bounds__(256) void cvt_inputs(const float* __restrict__ x0,
                                                  const float* __restrict__ x1,
                                                  const float* __restrict__ x2,
                                                  unsigned short* __restrict__ out) {
    const float* src = blockIdx.z == 0 ? x0 : (blockIdx.z == 1 ? x1 : x2);
    unsigned short* dst = out + (size_t)blockIdx.z * (4096 * 512);
    const int n = 4096 * 512 / 4;
    for (int i = blockIdx.x * blockDim.x + threadIdx.x; i < n; i += gridDim.x * blockDim.x) {
        float4 v = ((const float4*)src)[i];
        ushort4 o;
        o.x = f2bf(v.x); o.y = f2bf(v.y); o.z = f2bf(v.z); o.w = f2bf(v.w);
        ((ushort4*)dst)[i] = o;
    }
}

// ---------------- transpose+convert weights: W[512][512] -> Wt bf16 [N][K] ----------------
__global__ __launch_bounds__(256) void transpose_w(const float* __restrict__ w0,
                                                   const float* __restrict__ w1,
                                                   const float* __restrict__ w2,
                                                   const float* __restrict__ w3,
                                                   unsigned short* __restrict__ out) {
    const float* W = blockIdx.z == 0 ? w0 : blockIdx.z == 1 ? w1 : blockIdx.z == 2 ? w2 : w3;
    unsigned short* Wt = out + (size_t)blockIdx.z * (512 * 512);
    __shared__ float t[32][33];
    int tx = threadIdx.x, ty = threadIdx.y;
    int bx = blockIdx.x, by = blockIdx.y;
    #pragma unroll
    for (int i = 0; i < 4; ++i)
        t[ty + i * 8][tx] = W[(size_t)(by * 32 + ty + i * 8) * 512 + bx * 32 + tx];
    __syncthreads();
    #pragma unroll
    for (int i = 0; i < 4; ++i)
        Wt[(size_t)(bx * 32 + ty + i * 8) * 512 + by * 32 + tx] = f2bf(t[tx][ty + i * 8]);
}

// ---------------- pack mask row 0 per batch -> 1 bit/key (mask is q-uniform) --------------
__global__ __launch_bounds__(256) void pack_mask2(const int* __restrict__ mask,
                                                  unsigned long long* __restrict__ mp2) {
    int b = blockIdx.y, k = blockIdx.x * 256 + threadIdx.x;
    int v = mask[(size_t)b * 4194304 + k];
    unsigned long long bal = __ballot(v != 0);
    if ((threadIdx.x & 63) == 0) mp2[b * 32 + (k >> 6)] = bal;
}

// ---------------- GEMM: C[4096,512] = A_bf16 @ Wt^T + bias ----------------
// MODE 0: z in {K,V,Q}. z==0/2 -> qkv layout [z][B][H][L][64] (q scaled); z==1 -> VtB [bh][64][2048].
// MODE 1: out fp32 row-major [4096][512].
template <int MODE>
__global__ __launch_bounds__(256) void gemm_k(const unsigned short* __restrict__ Aall,
                                              const unsigned short* __restrict__ Wtall,
                                              const float* __restrict__ b0,
                                              const float* __restrict__ b1,
                                              const float* __restrict__ b2,
                                              void* __restrict__ outp,
                                              unsigned short* __restrict__ VtB) {
    const int z = blockIdx.z;
    const unsigned short* A  = Aall  + (size_t)z * (4096 * 512);
    const unsigned short* Bt = Wtall + (size_t)z * (512 * 512);
    const float* bias = (MODE == 0) ? (z == 0 ? b0 : (z == 1 ? b1 : b2)) : b0;

    __shared__ __align__(16) unsigned short As[128 * 64];   // XOR-swizzled chunks
    __shared__ __align__(16) unsigned short Bs[64 * 64];

    const int tid = threadIdx.x;
    const int wid = tid >> 6, lane = tid & 63, lr = lane & 15, lg = lane >> 4;
    const int wr = wid >> 1, wc = wid & 1;
    const int mblk = blockIdx.x * 128, nblk = blockIdx.y * 64;
    const int r7 = lr & 7;

    fx4 acc[4][2];
    #pragma unroll
    for (int mf = 0; mf < 4; ++mf)
        #pragma unroll
        for (int nf = 0; nf < 2; ++nf)
            #pragma unroll
            for (int j = 0; j < 4; ++j) acc[mf][nf][j] = 0.f;

    for (int kt = 0; kt < 8; ++kt) {
        __syncthreads();                         // WAR
        #pragma unroll
        for (int g = 0; g < 4; ++g) {            // A: 1024 chunks, 256/wave
            int ci = wid * 256 + g * 64 + lane;
            int r = ci >> 3, c = (ci & 7) ^ (r & 7);
            gl16(A + (size_t)(mblk + r) * 512 + kt * 64 + c * 8, &As[(wid * 256 + g * 64) * 8]);
        }
        #pragma unroll
        for (int g = 0; g < 2; ++g) {            // B: 512 chunks, 128/wave
            int ci = wid * 128 + g * 64 + lane;
            int r = ci >> 3, c = (ci & 7) ^ (r & 7);
            gl16(Bt + (size_t)(nblk + r) * 512 + kt * 64 + c * 8, &Bs[(wid * 128 + g * 64) * 8]);
        }
        __syncthreads();                         // RAW (compiler drains vmcnt)
        #pragma unroll
        for (int d = 0; d < 2; ++d) {
            sh8 af[4], bf[2];
            #pragma unroll
            for (int mf = 0; mf < 4; ++mf)
                af[mf] = *(const sh8*)&As[(wr * 64 + mf * 16 + lr) * 64 + (((d * 4 + lg) ^ r7) * 8)];
            #pragma unroll
            for (int nf = 0; nf < 2; ++nf)
                bf[nf] = *(const sh8*)&Bs[(wc * 32 + nf * 16 + lr) * 64 + (((d * 4 + lg) ^ r7) * 8)];
            #pragma unroll
            for (int mf = 0; mf < 4; ++mf)
                #pragma unroll
                for (int nf = 0; nf < 2; ++nf)
                    acc[mf][nf] = __builtin_amdgcn_mfma_f32_16x16x32_bf16(af[mf], bf[nf], acc[mf][nf], 0, 0, 0);
        }
    }

    if (MODE == 0 && z == 1) {
        // V: write transposed only -> VtB[(b*8+h)*64 + dd][lq]
        #pragma unroll
        for (int nf = 0; nf < 2; ++nf) {
            int n = nblk + wc * 32 + nf * 16 + lr;
            float bv = bias[n];
            int h = n >> 6, dd = n & 63;
            #pragma unroll
            for (int mf = 0; mf < 4; ++mf) {
                int m0 = mblk + wr * 64 + mf * 16 + lg * 4;
                int bb = m0 >> 11, lq = m0 & 2047;
                ushort4 o;
                o.x = f2bf(acc[mf][nf][0] + bv);
                o.y = f2bf(acc[mf][nf][1] + bv);
                o.z = f2bf(acc[mf][nf][2] + bv);
                o.w = f2bf(acc[mf][nf][3] + bv);
                *(ushort4*)(VtB + ((size_t)(bb * 8 + h) * 64 + dd) * 2048 + lq) = o;
            }
        }
    } else {
        #pragma unroll
        for (int nf = 0; nf < 2; ++nf) {
            int n = nblk + wc * 32 + nf * 16 + lr;
            float bv = bias[n];
            #pragma unroll
            for (int mf = 0; mf < 4; ++mf) {
                #pragma unroll
                for (int j = 0; j < 4; ++j) {
                    int m = mblk + wr * 64 + mf * 16 + lg * 4 + j;
                    float val = acc[mf][nf][j] + bv;
                    if (MODE == 0) {
                        if (z == 2) val *= 0.125f;      // 1/sqrt(64) folded into q
                        int bb = m >> 11, lq = m & 2047, h = n >> 6, dd = n & 63;
                        ((unsigned short*)outp)[(size_t)(((z * 2 + bb) * 8 + h) * 2048 + lq) * 64 + dd] = f2bf(val);
                    } else {
                        ((float*)outp)[(size_t)m * 512 + n] = val;
                    }
                }
            }
        }
    }
}

// ---------------- attention stats (pass 1): partial (m,l) per q row, ksplit=4 ------------
__global__ __launch_bounds__(256) void attn_stats(const unsigned short* __restrict__ qkv,
                                                  const unsigned long long* __restrict__ mp2,
                                                  float2* __restrict__ sp) {
    const int bid = blockIdx.x;
    const int swz = (bid & 7) * 256 + (bid >> 3);          // XCD-chunked (2048 % 8 == 0)
    const int qb = swz & 31, bh = (swz >> 5) & 15, ks = swz >> 9;
    const int b = bh >> 3;
    const unsigned short* Kg = qkv + (size_t)bh * 131072 + (size_t)ks * 512 * 64;
    const unsigned short* Qg = qkv + 2 * 2097152 + (size_t)bh * 131072 + (size_t)qb * 64 * 64;
    const int tid = threadIdx.x, w = tid >> 6, lane = tid & 63, lr = lane & 15, lg = lane >> 4;
    float2* spo = sp + (size_t)ks * 32768 + bh * 2048 + qb * 64;

    unsigned long long mws[8];
    bool any = false;
    #pragma unroll
    for (int kt = 0; kt < 8; ++kt) { mws[kt] = mp2[b * 32 + ks * 8 + kt]; any |= (mws[kt] != 0ull); }
    if (!any) {
        if (tid < 64) spo[tid] = make_float2(-3e38f, 0.f);
        return;
    }

    sh8 qf0 = *(const sh8*)(Qg + (w * 16 + lr) * 64 + lg * 8);
    sh8 qf1 = *(const sh8*)(Qg + (w * 16 + lr) * 64 + 32 + lg * 8);

    float m_ = -3e38f, l_ = 0.f;
    for (int kt = 0; kt < 8; ++kt) {
        unsigned long long mw = mws[kt];
        if (mw == 0ull) continue;
        const unsigned short* Kt = Kg + kt * 64 * 64;
        fx4 accs[4];
        #pragma unroll
        for (int mt = 0; mt < 4; ++mt) {
            sh8 kf0 = *(const sh8*)(Kt + (mt * 16 + lr) * 64 + lg * 8);
            sh8 kf1 = *(const sh8*)(Kt + (mt * 16 + lr) * 64 + 32 + lg * 8);
            fx4 zz; zz[0] = 0.f; zz[1] = 0.f; zz[2] = 0.f; zz[3] = 0.f;
            zz = __builtin_amdgcn_mfma_f32_16x16x32_bf16(kf0, qf0, zz, 0, 0, 0);
            accs[mt] = __builtin_amdgcn_mfma_f32_16x16x32_bf16(kf1, qf1, accs[mt] = zz, 0, 0, 0);
        }
        float sv[16];
        float tmax = -3e38f;
        if (mw == ~0ull) {
            #pragma unroll
            for (int mt = 0; mt < 4; ++mt)
                #pragma unroll
                for (int j = 0; j < 4; ++j) {
                    float s = accs[mt][j];
                    sv[mt * 4 + j] = s; tmax = fmaxf(tmax, s);
                }
        } else {
            #pragma unroll
            for (int mt = 0; mt < 4; ++mt)
                #pragma unroll
                for (int j = 0; j < 4; ++j) {
                    int kl = mt * 16 + lg * 4 + j;
                    bool ok = (mw >> kl) & 1ull;
                    float s = ok ? accs[mt][j] : -3e38f;
                    sv[mt * 4 + j] = s; tmax = fmaxf(tmax, s);
                }
        }
        float mnew = fmaxf(m_, tmax);
        float ps = 0.f;
        #pragma unroll
        for (int i = 0; i < 16; ++i) ps += __expf(sv[i] - mnew);
        l_ = l_ * __expf(m_ - mnew) + ps;
        m_ = mnew;
    }
    #pragma unroll
    for (int off = 16; off <= 32; off <<= 1) {
        float mo = __shfl_xor(m_, off), lo = __shfl_xor(l_, off);
        float mn = fmaxf(m_, mo);
        l_ = l_ * __expf(m_ - mn) + lo * __expf(mo - mn);
        m_ = mn;
    }
    if (lg == 0) spo[w * 16 + lr] = make_float2(m_, l_);
}

// ---------------- pass 2: recompute S^T, write normalized aw, PV partial ------------------
// Double-buffered global_load_lds pipeline with counted vmcnt; raw barriers.
__device__ __forceinline__ void stage_kv(const unsigned short* Kg, const unsigned short* Vg,
                                         unsigned short* sK, unsigned short* sV,
                                         int t, int w, int lane) {
    #pragma unroll
    for (int g = 0; g < 2; ++g) {
        int ci = w * 128 + g * 64 + lane;
        int r = ci >> 3, c = (ci & 7) ^ (r & 7);
        gl16(Kg + (size_t)(t * 64 + r) * 64 + c * 8, sK + (w * 128 + g * 64) * 8);
        gl16(Vg + (size_t)r * 2048 + t * 64 + c * 8, sV + (w * 128 + g * 64) * 8);
    }
}

__global__ __launch_bounds__(256) void attn_pass2(const unsigned short* __restrict__ qkv,
                                                  const unsigned short* __restrict__ Vt,
                                                  const unsigned long long* __restrict__ mp2,
                                                  const float2* __restrict__ sp,
                                                  float* __restrict__ aw,
                                                  float* __restrict__ ppart) {
    const int bid = blockIdx.x;
    const int swz = (bid & 7) * 128 + (bid >> 3);          // XCD-chunked (1024 % 8 == 0)
    const int qb = swz & 31, bh = (swz >> 5) & 15, ks = swz >> 9;
    const int b = bh >> 3, h = bh & 7;
    const unsigned short* Kg = qkv + (size_t)bh * 131072 + (size_t)ks * 1024 * 64;
    const unsigned short* Vg = Vt + (size_t)bh * 131072 + (size_t)ks * 1024;   // [64 d][2048 k]
    const unsigned short* Qg = qkv + 2 * 2097152 + (size_t)bh * 131072 + (size_t)qb * 4096;

    __shared__ __align__(16) unsigned short Ks[2][4096];
    __shared__ __align__(16) unsigned short Vs[2][4096];
    __shared__ __align__(16) unsigned short Pb[4096];

    const int tid = threadIdx.x, w = tid >> 6, lane = tid & 63, lr = lane & 15, lg = lane >> 4;
    const int r7 = lr & 7;
    const int q = qb * 64 + w * 16 + lr;

    // merge ksplit=4 stats partials -> (M, 1/L)
    float M = -3e38f, L = 0.f;
    float2 vv[4];
    #pragma unroll
    for (int s4 = 0; s4 < 4; ++s4) { vv[s4] = sp[(size_t)s4 * 32768 + bh * 2048 + q]; M = fmaxf(M, vv[s4].x); }
    #pragma unroll
    for (int s4 = 0; s4 < 4; ++s4) L += vv[s4].y * __expf(vv[s4].x - M);
    float rinv = (L > 0.f) ? 1.f / L : 0.f;
    if (L <= 0.f) M = 0.f;

    sh8 qf0 = *(const sh8*)(Qg + (w * 16 + lr) * 64 + lg * 8);
    sh8 qf1 = *(const sh8*)(Qg + (w * 16 + lr) * 64 + 32 + lg * 8);
    unsigned long long mwv = (lane < 16) ? mp2[b * 32 + ks * 16 + lane] : 0ull;

    fx4 acco[4];
    #pragma unroll
    for (int md = 0; md < 4; ++md) { acco[md][0] = 0.f; acco[md][1] = 0.f; acco[md][2] = 0.f; acco[md][3] = 0.f; }

    float* awb = aw + (size_t)bh * 4194304 + (size_t)q * 2048 + (size_t)ks * 1024;

    asm volatile("s_waitcnt vmcnt(0)" ::: "memory");   // clean VMEM FIFO before pipeline
    stage_kv(Kg, Vg, Ks[0], Vs[0], 0, w, lane);
    stage_kv(Kg, Vg, Ks[1], Vs[1], 1, w, lane);

    for (int kt = 0; kt < 16; ++kt) {
        if (kt >= 1 && kt <= 14)
            stage_kv(Kg, Vg, Ks[(kt + 1) & 1], Vs[(kt + 1) & 1], kt + 1, w, lane);
        // FIFO (steady): [L_cur x4][S_aw x4][L_next x4] -> vmcnt(8) retires L_cur only.
        if (kt == 0 || kt == 15) asm volatile("s_waitcnt vmcnt(4)" ::: "memory");
        else                     asm volatile("s_waitcnt vmcnt(8)" ::: "memory");
        asm volatile("s_barrier" ::: "memory");

        unsigned long long mw = __shfl(mwv, kt, 64);
        const unsigned short* KsB = Ks[kt & 1];
        const unsigned short* VsB = Vs[kt & 1];

        if (mw != 0ull) {
            fx4 accs[4];
            #pragma unroll
            for (int mt = 0; mt < 4; ++mt) {
                sh8 kf0 = *(const sh8*)&KsB[(mt * 16 + lr) * 64 + ((lg ^ r7) * 8)];
                sh8 kf1 = *(const sh8*)&KsB[(mt * 16 + lr) * 64 + (((4 + lg) ^ r7) * 8)];
                fx4 zz; zz[0] = 0.f; zz[1] = 0.f; zz[2] = 0.f; zz[3] = 0.f;
                zz = __builtin_amdgcn_mfma_f32_16x16x32_bf16(kf0, qf0, zz, 0, 0, 0);
                accs[mt] = __builtin_amdgcn_mfma_f32_16x16x32_bf16(kf1, qf1, zz, 0, 0, 0);
            }
            bool full = (mw == ~0ull);
            #pragma unroll
            for (int mt = 0; mt < 4; ++mt) {
                float4 pw;
                #pragma unroll
                for (int j = 0; j < 4; ++j) {
                    int kl = mt * 16 + lg * 4 + j;
                    bool ok = full || ((mw >> kl) & 1ull);
                    float p = ok ? __expf(accs[mt][j] - M) * rinv : 0.f;
                    ((float*)&pw)[j] = p;
                }
                *(float4*)(awb + kt * 64 + mt * 16 + lg * 4) = pw;
                // Pb XOR-swizzled: row=w*16+lr, chunk cc = mt*2+(lg>>1) at slot cc^r7, sub (lg&1)*4
                int sc = (mt * 2 + (lg >> 1)) ^ r7;
                *(uint2*)&Pb[(w * 16 + lr) * 64 + sc * 8 + (lg & 1) * 4] =
                    make_uint2(pk2(pw.x, pw.y), pk2(pw.z, pw.w));
            }
            asm volatile("s_waitcnt lgkmcnt(0)" ::: "memory");   // wave-private Pb RAW
            __builtin_amdgcn_sched_barrier(0);
            sh8 bp0 = *(const sh8*)&Pb[(w * 16 + lr) * 64 + ((lg ^ r7) * 8)];
            sh8 bp1 = *(const sh8*)&Pb[(w * 16 + lr) * 64 + (((4 + lg) ^ r7) * 8)];
            #pragma unroll
            for (int md = 0; md < 4; ++md) {
                sh8 vf0 = *(const sh8*)&VsB[(md * 16 + lr) * 64 + ((lg ^ r7) * 8)];
                sh8 vf1 = *(const sh8*)&VsB[(md * 16 + lr) * 64 + (((4 + lg) ^ r7) * 8)];
                acco[md] = __builtin_amdgcn_mfma_f32_16x16x32_bf16(vf0, bp0, acco[md], 0, 0, 0);
                acco[md] = __builtin_amdgcn_mfma_f32_16x16x32_bf16(vf1, bp1, acco[md], 0, 0, 0);
            }
        } else {
            float4 z4 = {0.f, 0.f, 0.f, 0.f};
            #pragma unroll
            for (int mt = 0; mt < 4; ++mt)      // exactly 4 stores: keeps vmcnt accounting
                *(float4*)(awb + kt * 64 + mt * 16 + lg * 4) = z4;
        }
        asm volatile("s_barrier" ::: "memory");  // WAR before next issue overwrites buffer
    }

    float* ppo = ppart + (size_t)ks * 2097152 + (size_t)(b * 2048 + qb * 64 + w * 16 + lr) * 512 + h * 64;
    #pragma unroll
    for (int md = 0; md < 4; ++md)
        *(fx4*)(ppo + md * 16 + lg * 4) = acco[md];
}

// ---------------- reduce PV partials -> cvb bf16 [4096][512] ------------------------------
__global__ __launch_bounds__(256) void pv_reduce(const float* __restrict__ pp,
                                                 unsigned short* __restrict__ cvb) {
    int i = blockIdx.x * 256 + threadIdx.x;
    float4 a = ((const float4*)pp)[i];
    float4 b = ((const float4*)(pp + 2097152))[i];
    ushort4 o;
    o.x = f2bf(a.x + b.x); o.y = f2bf(a.y + b.y);
    o.z = f2bf(a.z + b.z); o.w = f2bf(a.w + b.w);
    ((ushort4*)cvb)[i] = o;
}

// ---------------- launch ----------------
extern "C" void kernel_launch(void* const* d_in, const int* in_sizes, int n_in,
                              void* d_out, int out_size, void* d_ws, size_t ws_size,
                              hipStream_t stream) {
    const float* key_in   = (const float*)d_in[0];
    const float* value_in = (const float*)d_in[1];
    const float* query_in = (const float*)d_in[2];
    const float* Wk = (const float*)d_in[3];
    const float* bk = (const float*)d_in[4];
    const float* Wv = (const float*)d_in[5];
    const float* bv = (const float*)d_in[6];
    const float* Wq = (const float*)d_in[7];
    const float* bq = (const float*)d_in[8];
    const float* Wo = (const float*)d_in[9];
    const float* bo = (const float*)d_in[10];
    const int* mask = (const int*)d_in[11];

    char* ws = (char*)d_ws;
    float*          ppart = (float*)(ws);                       // 16.78M (attn) / in_bf 12.58M (pre)
    unsigned short* in_bf = (unsigned short*)(ws);
    unsigned short* qkv   = (unsigned short*)(ws + 16777216);   // 12.58M; cvb overlays K region after attn
    unsigned short* cvb   = (unsigned short*)(ws + 16777216);
    unsigned short* wt    = (unsigned short*)(ws + 29360128);   // 2.10M
    unsigned short* VtB   = (unsigned short*)(ws + 31457280);   // 4.19M
    unsigned long long* mp2 = (unsigned long long*)(ws + 35651584); // 512B (pad 1K)
    float2*         sp    = (float2*)(ws + 35652608);           // 1.05M -> ~36.7M total

    float* out_cv = (float*)d_out;
    float* out_aw = (float*)d_out + 2097152;

    cvt_inputs<<<dim3(512, 1, 3), 256, 0, stream>>>(key_in, value_in, query_in, in_bf);
    transpose_w<<<dim3(16, 16, 4), dim3(32, 8), 0, stream>>>(Wk, Wv, Wq, Wo, wt);
    pack_mask2<<<dim3(8, 2), 256, 0, stream>>>(mask, mp2);
    gemm_k<0><<<dim3(32, 8, 3), 256, 0, stream>>>(in_bf, wt, bk, bv, bq, qkv, VtB);
    attn_stats<<<dim3(2048), 256, 0, stream>>>(qkv, mp2, sp);
    attn_pass2<<<dim3(1024), 256, 0, stream>>>(qkv, VtB, mp2, sp, out_aw, ppart);
    pv_reduce<<<dim3(2048), 256, 0, stream>>>(ppart, cvb);
    gemm_k<1><<<dim3(32, 8, 1), 256, 0, stream>>>(cvb, wt + 3 * 262144, bo, bo, bo, out_cv, (unsigned short*)nullptr);
}

// Round 4
// 126.479 us; speedup vs baseline: 1.9682x; 1.4652x over previous
//
#include <hip/hip_runtime.h>

typedef short sh8 __attribute__((ext_vector_type(8)));   // 8 bf16
typedef float fx4 __attribute__((ext_vector_type(4)));   // MFMA accumulator

__device__ __forceinline__ unsigned short f2bf(float f) {
    union { float f; unsigned u; } v; v.f = f;
    unsigned r = v.u + 0x7FFFu + ((v.u >> 16) & 1u);   // RNE
    return (unsigned short)(r >> 16);
}
__device__ __forceinline__ unsigned pk2(float a, float b) {
    return (unsigned)f2bf(a) | ((unsigned)f2bf(b) << 16);
}
// async global->LDS, 16B per lane; LDS dest = wave-uniform base + lane*16
__device__ __forceinline__ void gl16(const unsigned short* g, unsigned short* l) {
    __builtin_amdgcn_global_load_lds(
        (const __attribute__((address_space(1))) unsigned int*)g,
        (__attribute__((address_space(3))) unsigned int*)l, 16, 0, 0);
}

// ---------------- prep: cvt inputs + transpose weights + pack mask (one kernel) -----------
__global__ __launch_bounds__(256) void prep(const float* __restrict__ x0,
                                            const float* __restrict__ x1,
                                            const float* __restrict__ x2,
                                            const float* __restrict__ w0,
                                            const float* __restrict__ w1,
                                            const float* __restrict__ w2,
                                            const float* __restrict__ w3,
                                            const int* __restrict__ mask,
                                            unsigned short* __restrict__ in_bf,
                                            unsigned short* __restrict__ wt,
                                            unsigned long long* __restrict__ mp2) {
    __shared__ float tw[32][33];
    const int bid = blockIdx.x, tid = threadIdx.x;
    if (bid < 1536) {                               // cvt: 3 inputs x 512 blocks
        const int z = bid >> 9, xb = bid & 511;
        const float* src = z == 0 ? x0 : (z == 1 ? x1 : x2);
        unsigned short* dst = in_bf + (size_t)z * 2097152;
        for (int i = xb * 256 + tid; i < 524288; i += 131072) {
            float4 v = ((const float4*)src)[i];
            ushort4 o;
            o.x = f2bf(v.x); o.y = f2bf(v.y); o.z = f2bf(v.z); o.w = f2bf(v.w);
            ((ushort4*)dst)[i] = o;
        }
    } else if (bid < 2560) {                        // transpose_w: 4 x (16x16) blocks
        const int t = bid - 1536;
        const int z = t >> 8, bx = t & 15, by = (t >> 4) & 15;
        const float* W = z == 0 ? w0 : z == 1 ? w1 : z == 2 ? w2 : w3;
        unsigned short* Wt = wt + (size_t)z * 262144;
        const int tx = tid & 31, ty = tid >> 5;
        #pragma unroll
        for (int i = 0; i < 4; ++i)
            tw[ty + i * 8][tx] = W[(size_t)(by * 32 + ty + i * 8) * 512 + bx * 32 + tx];
        __syncthreads();
        #pragma unroll
        for (int i = 0; i < 4; ++i)
            Wt[(size_t)(bx * 32 + ty + i * 8) * 512 + by * 32 + tx] = f2bf(tw[tx][ty + i * 8]);
    } else {                                        // pack_mask: 16 blocks (2 b x 8)
        const int p = bid - 2560;
        const int b = p >> 3, k = (p & 7) * 256 + tid;
        int v = mask[(size_t)b * 4194304 + k];
        unsigned long long bal = __ballot(v != 0);
        if ((tid & 63) == 0) mp2[b * 32 + (k >> 6)] = bal;
    }
}

// ---------------- GEMM: C[4096,512] = A_bf16 @ Wt^T + bias ----------------
// MODE 0: z in {K,V,Q}. z==0/2 -> qkv layout [z][B][H][L][64] (q scaled); z==1 -> VtB [bh][64][2048].
// MODE 1: out fp32 row-major [4096][512].
template <int MODE>
__global__ __launch_bounds__(256) void gemm_k(const unsigned short* __restrict__ Aall,
                                              const unsigned short* __restrict__ Wtall,
                                              const float* __restrict__ b0,
                                              const float* __restrict__ b1,
                                              const float* __restrict__ b2,
                                              void* __restrict__ outp,
                                              unsigned short* __restrict__ VtB) {
    const int z = blockIdx.z;
    const unsigned short* A  = Aall  + (size_t)z * (4096 * 512);
    const unsigned short* Bt = Wtall + (size_t)z * (512 * 512);
    const float* bias = (MODE == 0) ? (z == 0 ? b0 : (z == 1 ? b1 : b2)) : b0;

    __shared__ __align__(16) unsigned short As[128 * 64];   // XOR-swizzled chunks
    __shared__ __align__(16) unsigned short Bs[64 * 64];

    const int tid = threadIdx.x;
    const int wid = tid >> 6, lane = tid & 63, lr = lane & 15, lg = lane >> 4;
    const int wr = wid >> 1, wc = wid & 1;
    const int mblk = blockIdx.x * 128, nblk = blockIdx.y * 64;
    const int r7 = lr & 7;

    fx4 acc[4][2];
    #pragma unroll
    for (int mf = 0; mf < 4; ++mf)
        #pragma unroll
        for (int nf = 0; nf < 2; ++nf)
            #pragma unroll
            for (int j = 0; j < 4; ++j) acc[mf][nf][j] = 0.f;

    for (int kt = 0; kt < 8; ++kt) {
        __syncthreads();                         // WAR
        #pragma unroll
        for (int g = 0; g < 4; ++g) {            // A: 1024 chunks, 256/wave
            int ci = wid * 256 + g * 64 + lane;
            int r = ci >> 3, c = (ci & 7) ^ (r & 7);
            gl16(A + (size_t)(mblk + r) * 512 + kt * 64 + c * 8, &As[(wid * 256 + g * 64) * 8]);
        }
        #pragma unroll
        for (int g = 0; g < 2; ++g) {            // B: 512 chunks, 128/wave
            int ci = wid * 128 + g * 64 + lane;
            int r = ci >> 3, c = (ci & 7) ^ (r & 7);
            gl16(Bt + (size_t)(nblk + r) * 512 + kt * 64 + c * 8, &Bs[(wid * 128 + g * 64) * 8]);
        }
        __syncthreads();                         // RAW (compiler drains vmcnt)
        #pragma unroll
        for (int d = 0; d < 2; ++d) {
            sh8 af[4], bf[2];
            #pragma unroll
            for (int mf = 0; mf < 4; ++mf)
                af[mf] = *(const sh8*)&As[(wr * 64 + mf * 16 + lr) * 64 + (((d * 4 + lg) ^ r7) * 8)];
            #pragma unroll
            for (int nf = 0; nf < 2; ++nf)
                bf[nf] = *(const sh8*)&Bs[(wc * 32 + nf * 16 + lr) * 64 + (((d * 4 + lg) ^ r7) * 8)];
            #pragma unroll
            for (int mf = 0; mf < 4; ++mf)
                #pragma unroll
                for (int nf = 0; nf < 2; ++nf)
                    acc[mf][nf] = __builtin_amdgcn_mfma_f32_16x16x32_bf16(af[mf], bf[nf], acc[mf][nf], 0, 0, 0);
        }
    }

    if (MODE == 0 && z == 1) {
        // V: write transposed only -> VtB[(b*8+h)*64 + dd][lq]
        #pragma unroll
        for (int nf = 0; nf < 2; ++nf) {
            int n = nblk + wc * 32 + nf * 16 + lr;
            float bv = bias[n];
            int h = n >> 6, dd = n & 63;
            #pragma unroll
            for (int mf = 0; mf < 4; ++mf) {
                int m0 = mblk + wr * 64 + mf * 16 + lg * 4;
                int bb = m0 >> 11, lq = m0 & 2047;
                ushort4 o;
                o.x = f2bf(acc[mf][nf][0] + bv);
                o.y = f2bf(acc[mf][nf][1] + bv);
                o.z = f2bf(acc[mf][nf][2] + bv);
                o.w = f2bf(acc[mf][nf][3] + bv);
                *(ushort4*)(VtB + ((size_t)(bb * 8 + h) * 64 + dd) * 2048 + lq) = o;
            }
        }
    } else {
        #pragma unroll
        for (int nf = 0; nf < 2; ++nf) {
            int n = nblk + wc * 32 + nf * 16 + lr;
            float bv = bias[n];
            #pragma unroll
            for (int mf = 0; mf < 4; ++mf) {
                #pragma unroll
                for (int j = 0; j < 4; ++j) {
                    int m = mblk + wr * 64 + mf * 16 + lg * 4 + j;
                    float val = acc[mf][nf][j] + bv;
                    if (MODE == 0) {
                        if (z == 2) val *= 0.125f;      // 1/sqrt(64) folded into q
                        int bb = m >> 11, lq = m & 2047, h = n >> 6, dd = n & 63;
                        ((unsigned short*)outp)[(size_t)(((z * 2 + bb) * 8 + h) * 2048 + lq) * 64 + dd] = f2bf(val);
                    } else {
                        ((float*)outp)[(size_t)m * 512 + n] = val;
                    }
                }
            }
        }
    }
}

// ---------------- fused attention: stats (phase A) + aw/PV (phase B), one block per (qb,bh)
__device__ __forceinline__ void stage_k1(const unsigned short* Kg, unsigned short* sK,
                                         int t, int w, int lane) {
    #pragma unroll
    for (int g = 0; g < 2; ++g) {
        int ci = w * 128 + g * 64 + lane;
        int r = ci >> 3, c = (ci & 7) ^ (r & 7);
        gl16(Kg + (size_t)(t * 64 + r) * 64 + c * 8, sK + (w * 128 + g * 64) * 8);
    }
}
__device__ __forceinline__ void stage_kv(const unsigned short* Kg, const unsigned short* Vg,
                                         unsigned short* sK, unsigned short* sV,
                                         int t, int w, int lane) {
    #pragma unroll
    for (int g = 0; g < 2; ++g) {
        int ci = w * 128 + g * 64 + lane;
        int r = ci >> 3, c = (ci & 7) ^ (r & 7);
        gl16(Kg + (size_t)(t * 64 + r) * 64 + c * 8, sK + (w * 128 + g * 64) * 8);
        gl16(Vg + (size_t)r * 2048 + t * 64 + c * 8, sV + (w * 128 + g * 64) * 8);
    }
}

__global__ __launch_bounds__(256, 2) void attn_fused(const unsigned short* __restrict__ qkv,
                                                     const unsigned short* __restrict__ Vt,
                                                     const unsigned long long* __restrict__ mp2,
                                                     float* __restrict__ aw,
                                                     unsigned short* __restrict__ cv) {
    const int bid = blockIdx.x;
    const int swz = (bid & 7) * 64 + (bid >> 3);           // XCD-chunked (512 % 8 == 0)
    const int qb = swz & 31, bh = swz >> 5;
    const int b = bh >> 3, h = bh & 7;
    const unsigned short* Kg = qkv + (size_t)bh * 131072;
    const unsigned short* Vg = Vt + (size_t)bh * 131072;    // [64 d][2048 k]
    const unsigned short* Qg = qkv + 2 * 2097152 + (size_t)bh * 131072 + (size_t)qb * 4096;

    __shared__ __align__(16) unsigned short Ks[2][4096];
    __shared__ __align__(16) unsigned short Vs[2][4096];
    __shared__ __align__(16) unsigned short Pb[4096];

    const int tid = threadIdx.x, w = tid >> 6, lane = tid & 63, lr = lane & 15, lg = lane >> 4;
    const int r7 = lr & 7;
    const int q = qb * 64 + w * 16 + lr;

    sh8 qf0 = *(const sh8*)(Qg + (w * 16 + lr) * 64 + lg * 8);
    sh8 qf1 = *(const sh8*)(Qg + (w * 16 + lr) * 64 + 32 + lg * 8);
    unsigned long long mwv = (lane < 32) ? mp2[b * 32 + lane] : 0ull;

    // ---------- phase A: full-row softmax stats, K-only dbuf pipeline ----------
    float m_ = -3e38f, l_ = 0.f;
    asm volatile("s_waitcnt vmcnt(0)" ::: "memory");
    stage_k1(Kg, Ks[0], 0, w, lane);
    stage_k1(Kg, Ks[1], 1, w, lane);
    for (int kt = 0; kt < 32; ++kt) {
        if (kt >= 1 && kt <= 30)
            stage_k1(Kg, Ks[(kt + 1) & 1], kt + 1, w, lane);
        if (kt == 31) asm volatile("s_waitcnt vmcnt(0)" ::: "memory");
        else          asm volatile("s_waitcnt vmcnt(2)" ::: "memory");
        asm volatile("s_barrier" ::: "memory");
        unsigned long long mw = __shfl(mwv, kt, 64);
        if (mw != 0ull) {
            const unsigned short* KsB = Ks[kt & 1];
            fx4 accs[4];
            #pragma unroll
            for (int mt = 0; mt < 4; ++mt) {
                sh8 kf0 = *(const sh8*)&KsB[(mt * 16 + lr) * 64 + ((lg ^ r7) * 8)];
                sh8 kf1 = *(const sh8*)&KsB[(mt * 16 + lr) * 64 + (((4 + lg) ^ r7) * 8)];
                fx4 zz; zz[0] = 0.f; zz[1] = 0.f; zz[2] = 0.f; zz[3] = 0.f;
                zz = __builtin_amdgcn_mfma_f32_16x16x32_bf16(kf0, qf0, zz, 0, 0, 0);
                accs[mt] = __builtin_amdgcn_mfma_f32_16x16x32_bf16(kf1, qf1, zz, 0, 0, 0);
            }
            float sv[16], tmax = -3e38f;
            if (mw == ~0ull) {
                #pragma unroll
                for (int mt = 0; mt < 4; ++mt)
                    #pragma unroll
                    for (int j = 0; j < 4; ++j) {
                        float s = accs[mt][j];
                        sv[mt * 4 + j] = s; tmax = fmaxf(tmax, s);
                    }
            } else {
                #pragma unroll
                for (int mt = 0; mt < 4; ++mt)
                    #pragma unroll
                    for (int j = 0; j < 4; ++j) {
                        int kl = mt * 16 + lg * 4 + j;
                        bool ok = (mw >> kl) & 1ull;
                        float s = ok ? accs[mt][j] : -3e38f;
                        sv[mt * 4 + j] = s; tmax = fmaxf(tmax, s);
                    }
            }
            float mnew = fmaxf(m_, tmax);
            float ps = 0.f;
            #pragma unroll
            for (int i = 0; i < 16; ++i) ps += __expf(sv[i] - mnew);
            l_ = l_ * __expf(m_ - mnew) + ps;
            m_ = mnew;
        }
        asm volatile("s_barrier" ::: "memory");
    }
    // butterfly merge across lg groups -> every lane holds full-row (M, L)
    #pragma unroll
    for (int off = 16; off <= 32; off <<= 1) {
        float mo = __shfl_xor(m_, off), lo = __shfl_xor(l_, off);
        float mn = fmaxf(m_, mo);
        l_ = l_ * __expf(m_ - mn) + lo * __expf(mo - mn);
        m_ = mn;
    }
    const float M = (l_ > 0.f) ? m_ : 0.f;
    const float rinv = (l_ > 0.f) ? 1.f / l_ : 0.f;

    // ---------- phase B: recompute S^T, write normalized aw, accumulate PV ----------
    fx4 acco[4];
    #pragma unroll
    for (int md = 0; md < 4; ++md) { acco[md][0] = 0.f; acco[md][1] = 0.f; acco[md][2] = 0.f; acco[md][3] = 0.f; }
    float* awb = aw + (size_t)bh * 4194304 + (size_t)q * 2048;

    asm volatile("s_waitcnt vmcnt(0)" ::: "memory");
    stage_kv(Kg, Vg, Ks[0], Vs[0], 0, w, lane);
    stage_kv(Kg, Vg, Ks[1], Vs[1], 1, w, lane);

    for (int kt = 0; kt < 32; ++kt) {
        if (kt >= 1 && kt <= 30)
            stage_kv(Kg, Vg, Ks[(kt + 1) & 1], Vs[(kt + 1) & 1], kt + 1, w, lane);
        // FIFO (steady): [L_cur x4][S_aw x4][L_next x4] -> vmcnt(8) retires L_cur only.
        if (kt == 0 || kt == 31) asm volatile("s_waitcnt vmcnt(4)" ::: "memory");
        else                     asm volatile("s_waitcnt vmcnt(8)" ::: "memory");
        asm volatile("s_barrier" ::: "memory");

        unsigned long long mw = __shfl(mwv, kt, 64);
        const unsigned short* KsB = Ks[kt & 1];
        const unsigned short* VsB = Vs[kt & 1];

        if (mw != 0ull) {
            fx4 accs[4];
            #pragma unroll
            for (int mt = 0; mt < 4; ++mt) {
                sh8 kf0 = *(const sh8*)&KsB[(mt * 16 + lr) * 64 + ((lg ^ r7) * 8)];
                sh8 kf1 = *(const sh8*)&KsB[(mt * 16 + lr) * 64 + (((4 + lg) ^ r7) * 8)];
                fx4 zz; zz[0] = 0.f; zz[1] = 0.f; zz[2] = 0.f; zz[3] = 0.f;
                zz = __builtin_amdgcn_mfma_f32_16x16x32_bf16(kf0, qf0, zz, 0, 0, 0);
                accs[mt] = __builtin_amdgcn_mfma_f32_16x16x32_bf16(kf1, qf1, zz, 0, 0, 0);
            }
            bool full = (mw == ~0ull);
            #pragma unroll
            for (int mt = 0; mt < 4; ++mt) {
                float4 pw;
                #pragma unroll
                for (int j = 0; j < 4; ++j) {
                    int kl = mt * 16 + lg * 4 + j;
                    bool ok = full || ((mw >> kl) & 1ull);
                    float p = ok ? __expf(accs[mt][j] - M) * rinv : 0.f;
                    ((float*)&pw)[j] = p;
                }
                *(float4*)(awb + kt * 64 + mt * 16 + lg * 4) = pw;
                // Pb XOR-swizzled: row=w*16+lr, chunk cc = mt*2+(lg>>1) at slot cc^r7, sub (lg&1)*4
                int sc = (mt * 2 + (lg >> 1)) ^ r7;
                *(uint2*)&Pb[(w * 16 + lr) * 64 + sc * 8 + (lg & 1) * 4] =
                    make_uint2(pk2(pw.x, pw.y), pk2(pw.z, pw.w));
            }
            asm volatile("s_waitcnt lgkmcnt(0)" ::: "memory");   // wave-private Pb RAW
            __builtin_amdgcn_sched_barrier(0);
            sh8 bp0 = *(const sh8*)&Pb[(w * 16 + lr) * 64 + ((lg ^ r7) * 8)];
            sh8 bp1 = *(const sh8*)&Pb[(w * 16 + lr) * 64 + (((4 + lg) ^ r7) * 8)];
            #pragma unroll
            for (int md = 0; md < 4; ++md) {
                sh8 vf0 = *(const sh8*)&VsB[(md * 16 + lr) * 64 + ((lg ^ r7) * 8)];
                sh8 vf1 = *(const sh8*)&VsB[(md * 16 + lr) * 64 + (((4 + lg) ^ r7) * 8)];
                acco[md] = __builtin_amdgcn_mfma_f32_16x16x32_bf16(vf0, bp0, acco[md], 0, 0, 0);
                acco[md] = __builtin_amdgcn_mfma_f32_16x16x32_bf16(vf1, bp1, acco[md], 0, 0, 0);
            }
        } else {
            float4 z4 = {0.f, 0.f, 0.f, 0.f};
            #pragma unroll
            for (int mt = 0; mt < 4; ++mt)      // exactly 4 stores: keeps vmcnt accounting
                *(float4*)(awb + kt * 64 + mt * 16 + lg * 4) = z4;
        }
        asm volatile("s_barrier" ::: "memory");  // WAR before next issue overwrites buffer
    }

    // epilogue: complete PV row -> cvb bf16 [4096][512]
    #pragma unroll
    for (int md = 0; md < 4; ++md) {
        ushort4 o;
        o.x = f2bf(acco[md][0]); o.y = f2bf(acco[md][1]);
        o.z = f2bf(acco[md][2]); o.w = f2bf(acco[md][3]);
        *(ushort4*)(cv + (size_t)(b * 2048 + q) * 512 + h * 64 + md * 16 + lg * 4) = o;
    }
}

// ---------------- launch ----------------
extern "C" void kernel_launch(void* const* d_in, const int* in_sizes, int n_in,
                              void* d_out, int out_size, void* d_ws, size_t ws_size,
                              hipStream_t stream) {
    const float* key_in   = (const float*)d_in[0];
    const float* value_in = (const float*)d_in[1];
    const float* query_in = (const float*)d_in[2];
    const float* Wk = (const float*)d_in[3];
    const float* bk = (const float*)d_in[4];
    const float* Wv = (const float*)d_in[5];
    const float* bv = (const float*)d_in[6];
    const float* Wq = (const float*)d_in[7];
    const float* bq = (const float*)d_in[8];
    const float* Wo = (const float*)d_in[9];
    const float* bo = (const float*)d_in[10];
    const int* mask = (const int*)d_in[11];

    char* ws = (char*)d_ws;
    unsigned short* in_bf = (unsigned short*)(ws);                  // 12.58M
    unsigned short* qkv   = (unsigned short*)(ws + 12582912);       // 12.58M: K slot0, Q slot2
    unsigned short* cvb   = (unsigned short*)(ws + 12582912 + 4194304); // overlays unused V slot1
    unsigned short* wt    = (unsigned short*)(ws + 25165824);       // 2.10M
    unsigned short* VtB   = (unsigned short*)(ws + 27262976);       // 4.19M
    unsigned long long* mp2 = (unsigned long long*)(ws + 31457280); // 512 B

    float* out_cv = (float*)d_out;
    float* out_aw = (float*)d_out + 2097152;

    prep<<<dim3(2576), 256, 0, stream>>>(key_in, value_in, query_in,
                                         Wk, Wv, Wq, Wo, mask, in_bf, wt, mp2);
    gemm_k<0><<<dim3(32, 8, 3), 256, 0, stream>>>(in_bf, wt, bk, bv, bq, qkv, VtB);
    attn_fused<<<dim3(512), 256, 0, stream>>>(qkv, VtB, mp2, out_aw, cvb);
    gemm_k<1><<<dim3(32, 8, 1), 256, 0, stream>>>(cvb, wt + 3 * 262144, bo, bo, bo, out_cv, (unsigned short*)nullptr);
}